// Round 1
// baseline (838.075 us; speedup 1.0000x reference)
//
#include <hip/hip_runtime.h>
#include <hip/hip_bf16.h>

#define HW    16384   // 128*128
#define IMW   128
#define IMH   128
#define CIN   256
#define CR    64
#define G     16
#define GC    16

// ---------------------------------------------------------------------------
// K1: 1x1 conv 256->64.  y1[b,o,p] = b1[o] + sum_c w1[o,c] * x[b,c,p]
// Block: 256 threads = 256 consecutive pixels. Grid: B * (HW/256) = 512.
// w1 (64KB) staged in LDS; all reads broadcast (uniform address) -> no
// bank conflicts. acc[64] per thread.
// ---------------------------------------------------------------------------
__global__ __launch_bounds__(256) void k_conv1(const float* __restrict__ x,
                                               const float* __restrict__ w1,
                                               const float* __restrict__ b1,
                                               float* __restrict__ y1) {
  __shared__ float w1s[CR * CIN];
  const int tid = threadIdx.x;
#pragma unroll
  for (int i = 0; i < 64; ++i) w1s[i * 256 + tid] = w1[i * 256 + tid];
  __syncthreads();

  const int blk = blockIdx.x;          // b*64 + tile
  const int b   = blk >> 6;
  const int p   = (blk & 63) * 256 + tid;
  const float* xb = x + (size_t)b * CIN * HW + p;

  float acc[CR];
#pragma unroll
  for (int o = 0; o < CR; ++o) acc[o] = b1[o];

  for (int c = 0; c < CIN; c += 4) {
    const float x0 = xb[(size_t)(c + 0) * HW];
    const float x1 = xb[(size_t)(c + 1) * HW];
    const float x2 = xb[(size_t)(c + 2) * HW];
    const float x3 = xb[(size_t)(c + 3) * HW];
#pragma unroll
    for (int o = 0; o < CR; ++o) {
      const float4 wq = *(const float4*)&w1s[o * 256 + c];
      acc[o] += wq.x * x0 + wq.y * x1 + wq.z * x2 + wq.w * x3;
    }
  }

  float* yb = y1 + (size_t)b * CR * HW + p;
#pragma unroll
  for (int o = 0; o < CR; ++o) yb[(size_t)o * HW] = acc[o];
}

// ---------------------------------------------------------------------------
// K2: depthwise 3x3 over y1 (64 ch), zero pad 1.
// Block: 256 = 2 rows x 128 cols of one (b,c) plane. Grid: 8*64*64 = 32768.
// ---------------------------------------------------------------------------
__global__ __launch_bounds__(256) void k_dw(const float* __restrict__ y1,
                                            const float* __restrict__ wd,
                                            const float* __restrict__ bd,
                                            float* __restrict__ y2) {
  const int blk = blockIdx.x;
  const int h2  = blk & 63;
  const int bc  = blk >> 6;            // b*64 + c, in [0,512)
  const int c   = bc & 63;
  const int w   = threadIdx.x & 127;
  const int h   = h2 * 2 + (threadIdx.x >> 7);

  const float* src = y1 + (size_t)bc * HW;
  float wv[9];
#pragma unroll
  for (int j = 0; j < 9; ++j) wv[j] = wd[c * 9 + j];

  float acc = bd[c];
#pragma unroll
  for (int kh = 0; kh < 3; ++kh) {
    const int hh = h + kh - 1;
    if (hh < 0 || hh >= IMH) continue;
#pragma unroll
    for (int kw = 0; kw < 3; ++kw) {
      const int ww = w + kw - 1;
      if (ww < 0 || ww >= IMW) continue;
      acc += wv[kh * 3 + kw] * src[hh * IMW + ww];
    }
  }
  y2[(size_t)bc * HW + h * IMW + w] = acc;
}

// ---------------------------------------------------------------------------
// K3: fused conv2 (64->144) + involution.
// Block: 256 threads = one 16x16 pixel tile. Grid: B * 64 = 512.
// Stage y2 tile (64ch x 256px = 64KB) in LDS; per group compute the 9
// per-pixel dynamic weights in registers (w2/b2 via uniform scalar loads),
// then apply the 9 taps to the group's 16 x-channels (L1-cached reads).
// ---------------------------------------------------------------------------
__global__ __launch_bounds__(256) void k_invol(const float* __restrict__ x,
                                               const float* __restrict__ y2,
                                               const float* __restrict__ w2,
                                               const float* __restrict__ b2,
                                               float* __restrict__ out) {
  __shared__ float ys[CR][256];
  const int blk  = blockIdx.x;         // b*64 + tile
  const int b    = blk >> 6;
  const int tile = blk & 63;           // 8x8 tiles of 16x16
  const int h0   = (tile >> 3) * 16;
  const int w0   = (tile & 7) * 16;
  const int tid  = threadIdx.x;
  const int tr   = tid >> 4;           // row within tile
  const int tc   = tid & 15;           // col within tile

  // load y2 tile
  const float* y2b = y2 + (size_t)b * CR * HW + h0 * IMW + w0;
#pragma unroll
  for (int c = 0; c < CR; ++c) ys[c][tid] = y2b[(size_t)c * HW + tr * IMW + tc];
  __syncthreads();

  const int h = h0 + tr;
  const int w = w0 + tc;
  const float* xb = x + (size_t)b * CIN * HW;
  float*       ob = out + (size_t)b * CIN * HW;

  for (int g = 0; g < G; ++g) {
    // dynamic 3x3 weights for this thread's pixel, this group
    float wv[9];
#pragma unroll
    for (int j = 0; j < 9; ++j) wv[j] = b2[g * 9 + j];
#pragma unroll 4
    for (int c = 0; c < CR; ++c) {
      const float yv = ys[c][tid];
#pragma unroll
      for (int j = 0; j < 9; ++j) wv[j] += w2[(g * 9 + j) * CR + c] * yv;
    }
    // involution over the 16 channels of this group
#pragma unroll
    for (int cc = 0; cc < GC; ++cc) {
      const int ch = g * GC + cc;
      const float* xc = xb + (size_t)ch * HW;
      float acc = 0.f;
#pragma unroll
      for (int kh = 0; kh < 3; ++kh) {
        const int hh = h + kh - 1;
        if (hh < 0 || hh >= IMH) continue;
#pragma unroll
        for (int kw = 0; kw < 3; ++kw) {
          const int ww = w + kw - 1;
          if (ww < 0 || ww >= IMW) continue;
          acc += wv[kh * 3 + kw] * xc[hh * IMW + ww];
        }
      }
      ob[(size_t)ch * HW + h * IMW + w] = acc;
    }
  }
}

extern "C" void kernel_launch(void* const* d_in, const int* in_sizes, int n_in,
                              void* d_out, int out_size, void* d_ws, size_t ws_size,
                              hipStream_t stream) {
  const float* x  = (const float*)d_in[0];
  const float* w1 = (const float*)d_in[1];
  const float* b1 = (const float*)d_in[2];
  const float* wd = (const float*)d_in[3];
  const float* bd = (const float*)d_in[4];
  const float* w2 = (const float*)d_in[5];
  const float* b2 = (const float*)d_in[6];
  float* out = (float*)d_out;

  float* y1 = (float*)d_ws;                       // 8*64*16384 f32 = 33.5 MB
  float* y2 = y1 + (size_t)8 * CR * HW;           // another 33.5 MB

  k_conv1<<<dim3(512), dim3(256), 0, stream>>>(x, w1, b1, y1);
  k_dw<<<dim3(32768), dim3(256), 0, stream>>>(y1, wd, bd, y2);
  k_invol<<<dim3(512), dim3(256), 0, stream>>>(x, y2, w2, b2, out);
}

// Round 2
// 710.339 us; speedup vs baseline: 1.1798x; 1.1798x over previous
//
#include <hip/hip_runtime.h>
#include <hip/hip_bf16.h>

#define HW    16384   // 128*128
#define IMW   128
#define IMH   128
#define CIN   256
#define CR    64
#define G     16
#define GC    16

// ---------------------------------------------------------------------------
// K1: 1x1 conv 256->64.  y1[b,o,p] = b1[o] + sum_c w1[o,c] * x[b,c,p]
// Block: 256 threads = 256 consecutive pixels. Grid: B * (HW/256) = 512.
// w1 read with wave-uniform indices -> s_load + v_fmac with SGPR operand
// (scalar pipe, parallel to VALU). No LDS (previous version was
// ds_read-throughput-bound at ~4096 b128 reads/thread).
// ---------------------------------------------------------------------------
__global__ __launch_bounds__(256) void k_conv1(const float* __restrict__ x,
                                               const float* __restrict__ w1,
                                               const float* __restrict__ b1,
                                               float* __restrict__ y1) {
  const int blk = blockIdx.x;          // b*64 + tile
  const int b   = blk >> 6;
  const int p   = (blk & 63) * 256 + threadIdx.x;
  const float* xb = x + (size_t)b * CIN * HW + p;

  float acc[CR];
#pragma unroll
  for (int o = 0; o < CR; ++o) acc[o] = b1[o];

#pragma unroll 1
  for (int c = 0; c < CIN; c += 4) {
    const float x0 = xb[(size_t)(c + 0) * HW];
    const float x1 = xb[(size_t)(c + 1) * HW];
    const float x2 = xb[(size_t)(c + 2) * HW];
    const float x3 = xb[(size_t)(c + 3) * HW];
#pragma unroll
    for (int o = 0; o < CR; ++o) {
      const float4 wq = *(const float4*)(w1 + o * CIN + c);  // uniform -> s_load
      acc[o] += wq.x * x0 + wq.y * x1 + wq.z * x2 + wq.w * x3;
    }
  }

  float* yb = y1 + (size_t)b * CR * HW + p;
#pragma unroll
  for (int o = 0; o < CR; ++o) yb[(size_t)o * HW] = acc[o];
}

// ---------------------------------------------------------------------------
// K2: depthwise 3x3 over y1 (64 ch), zero pad 1.
// Block: 256 = 2 rows x 128 cols of one (b,c) plane. Grid: 8*64*64 = 32768.
// ---------------------------------------------------------------------------
__global__ __launch_bounds__(256) void k_dw(const float* __restrict__ y1,
                                            const float* __restrict__ wd,
                                            const float* __restrict__ bd,
                                            float* __restrict__ y2) {
  const int blk = blockIdx.x;
  const int h2  = blk & 63;
  const int bc  = blk >> 6;            // b*64 + c, in [0,512)
  const int c   = bc & 63;
  const int w   = threadIdx.x & 127;
  const int h   = h2 * 2 + (threadIdx.x >> 7);

  const float* src = y1 + (size_t)bc * HW;
  float wv[9];
#pragma unroll
  for (int j = 0; j < 9; ++j) wv[j] = wd[c * 9 + j];

  float acc = bd[c];
#pragma unroll
  for (int kh = 0; kh < 3; ++kh) {
    const int hh = h + kh - 1;
    if (hh < 0 || hh >= IMH) continue;
#pragma unroll
    for (int kw = 0; kw < 3; ++kw) {
      const int ww = w + kw - 1;
      if (ww < 0 || ww >= IMW) continue;
      acc += wv[kh * 3 + kw] * src[hh * IMW + ww];
    }
  }
  y2[(size_t)bc * HW + h * IMW + w] = acc;
}

// ---------------------------------------------------------------------------
// K3: fused conv2 (64->144) + involution, NO materialized weight tensor.
// Block: 256 threads = one 16x16 pixel tile, handling 8 of the 16 groups.
// Grid: B * 2 * 64 = 1024 blocks (4 blocks/CU, 16 waves/CU).
// Phase 1: per-thread weight-gen for its pixel, 8 groups x 9 taps = 72 accs;
//          y2 read coalesced from global, w2/b2 via uniform scalar loads.
// Phase 2: per group, stage 16 x-channels (18x18 halo = 20.7 KB LDS),
//          9-tap involution from LDS, coalesced store.
// ---------------------------------------------------------------------------
__global__ __launch_bounds__(256) void k_conv2invol(const float* __restrict__ x,
                                                    const float* __restrict__ y2,
                                                    const float* __restrict__ w2,
                                                    const float* __restrict__ b2,
                                                    float* __restrict__ out) {
  __shared__ float xs[GC * 324];       // one group's 16 channels, 18x18 halo

  const int blk  = blockIdx.x;         // (b*2 + gh)*64 + tile
  const int tile = blk & 63;
  const int gh   = (blk >> 6) & 1;     // which half of the 16 groups
  const int b    = blk >> 7;
  const int h0   = (tile >> 3) * 16;
  const int w0   = (tile & 7) * 16;
  const int tid  = threadIdx.x;
  const int tr   = tid >> 4;
  const int tc   = tid & 15;
  const int h    = h0 + tr;
  const int w    = w0 + tc;
  const int p    = h * IMW + w;

  // ---- phase 1: dynamic weights for this pixel, groups gh*8 .. gh*8+7 ----
  float wv[8][9];
#pragma unroll
  for (int q = 0; q < 8; ++q)
#pragma unroll
    for (int j = 0; j < 9; ++j) wv[q][j] = b2[(gh * 8 + q) * 9 + j];

  const float* y2p = y2 + (size_t)b * CR * HW + p;
  const float* w2g = w2 + (size_t)(gh * 8) * 9 * CR;   // [72][64]
#pragma unroll 1
  for (int c = 0; c < CR; ++c) {
    const float yv = y2p[(size_t)c * HW];
#pragma unroll
    for (int q = 0; q < 8; ++q)
#pragma unroll
      for (int j = 0; j < 9; ++j)
        wv[q][j] += w2g[(q * 9 + j) * CR + c] * yv;   // uniform -> s_load
  }

  // ---- phase 2: involution, one group at a time through LDS ----
  const float* xb = x + (size_t)b * CIN * HW;
  float*       ob = out + (size_t)b * CIN * HW;

#pragma unroll 1
  for (int q = 0; q < 8; ++q) {
    const int g = gh * 8 + q;
    __syncthreads();                   // xs reuse safety
    for (int i = tid; i < GC * 324; i += 256) {
      const int ch = i / 324;
      const int r  = (i - ch * 324) / 18;
      const int cc = i - ch * 324 - r * 18;
      const int hh = h0 + r - 1;
      const int ww = w0 + cc - 1;
      float v = 0.f;
      if (hh >= 0 && hh < IMH && ww >= 0 && ww < IMW)
        v = xb[(size_t)(g * GC + ch) * HW + hh * IMW + ww];
      xs[i] = v;
    }
    __syncthreads();

#pragma unroll 2
    for (int cc = 0; cc < GC; ++cc) {
      const float* xc = xs + cc * 324 + tr * 18 + tc;  // top-left tap
      float acc = 0.f;
#pragma unroll
      for (int kh = 0; kh < 3; ++kh)
#pragma unroll
        for (int kw = 0; kw < 3; ++kw)
          acc += wv[q][kh * 3 + kw] * xc[kh * 18 + kw];
      ob[(size_t)(g * GC + cc) * HW + p] = acc;
    }
  }
}

extern "C" void kernel_launch(void* const* d_in, const int* in_sizes, int n_in,
                              void* d_out, int out_size, void* d_ws, size_t ws_size,
                              hipStream_t stream) {
  const float* x  = (const float*)d_in[0];
  const float* w1 = (const float*)d_in[1];
  const float* b1 = (const float*)d_in[2];
  const float* wd = (const float*)d_in[3];
  const float* bd = (const float*)d_in[4];
  const float* w2 = (const float*)d_in[5];
  const float* b2 = (const float*)d_in[6];
  float* out = (float*)d_out;

  float* y1 = (float*)d_ws;                       // 8*64*16384 f32 = 33.5 MB
  float* y2 = y1 + (size_t)8 * CR * HW;           // another 33.5 MB

  k_conv1<<<dim3(512), dim3(256), 0, stream>>>(x, w1, b1, y1);
  k_dw<<<dim3(32768), dim3(256), 0, stream>>>(y1, wd, bd, y2);
  k_conv2invol<<<dim3(1024), dim3(256), 0, stream>>>(x, y2, w2, b2, out);
}

// Round 3
// 491.295 us; speedup vs baseline: 1.7058x; 1.4458x over previous
//
#include <hip/hip_runtime.h>
#include <hip/hip_bf16.h>

#define HW    16384   // 128*128
#define IMW   128
#define IMH   128
#define CIN   256
#define CR    64
#define G     16
#define GC    16

// ---------------------------------------------------------------------------
// K1: 1x1 conv 256->64, split into 2 output-halves for occupancy.
// Grid: B * 2 * 64 = 1024 blocks (4/CU, 16 waves/CU). Each thread: 1 pixel,
// 32 output channels. w1 via uniform s_load (scalar pipe); x loads software-
// pipelined 4 channels ahead.
// ---------------------------------------------------------------------------
__global__ __launch_bounds__(256) void k_conv1(const float* __restrict__ x,
                                               const float* __restrict__ w1,
                                               const float* __restrict__ b1,
                                               float* __restrict__ y1) {
  const int blk  = blockIdx.x;          // b*128 + half*64 + tile
  const int b    = blk >> 7;
  const int half = (blk >> 6) & 1;
  const int p    = (blk & 63) * 256 + threadIdx.x;
  const float* xb  = x  + (size_t)b * CIN * HW + p;
  const float* w1h = w1 + half * 32 * CIN;

  float acc[32];
#pragma unroll
  for (int o = 0; o < 32; ++o) acc[o] = b1[half * 32 + o];

  float c0 = xb[0], c1 = xb[HW], c2 = xb[2 * HW], c3 = xb[3 * HW];
#pragma unroll 1
  for (int c = 0; c < CIN; c += 4) {
    const int cn = (c + 4) & (CIN - 1);        // wraps to 0 on last iter (dummy)
    const float n0 = xb[(size_t)(cn + 0) * HW];
    const float n1 = xb[(size_t)(cn + 1) * HW];
    const float n2 = xb[(size_t)(cn + 2) * HW];
    const float n3 = xb[(size_t)(cn + 3) * HW];
#pragma unroll
    for (int o = 0; o < 32; ++o) {
      const float4 wq = *(const float4*)(w1h + o * CIN + c);  // uniform -> s_load
      acc[o] += wq.x * c0 + wq.y * c1 + wq.z * c2 + wq.w * c3;
    }
    c0 = n0; c1 = n1; c2 = n2; c3 = n3;
  }

  float* yb = y1 + (size_t)b * CR * HW + (size_t)(half * 32) * HW + p;
#pragma unroll
  for (int o = 0; o < 32; ++o) yb[(size_t)o * HW] = acc[o];
}

// ---------------------------------------------------------------------------
// K2: depthwise 3x3 over y1 (64 ch), zero pad 1.
// Block: 256 = 2 rows x 128 cols of one (b,c) plane. Grid: 8*64*64 = 32768.
// ---------------------------------------------------------------------------
__global__ __launch_bounds__(256) void k_dw(const float* __restrict__ y1,
                                            const float* __restrict__ wd,
                                            const float* __restrict__ bd,
                                            float* __restrict__ y2) {
  const int blk = blockIdx.x;
  const int h2  = blk & 63;
  const int bc  = blk >> 6;            // b*64 + c, in [0,512)
  const int c   = bc & 63;
  const int w   = threadIdx.x & 127;
  const int h   = h2 * 2 + (threadIdx.x >> 7);

  const float* src = y1 + (size_t)bc * HW;
  float wv[9];
#pragma unroll
  for (int j = 0; j < 9; ++j) wv[j] = wd[c * 9 + j];

  float acc = bd[c];
#pragma unroll
  for (int kh = 0; kh < 3; ++kh) {
    const int hh = h + kh - 1;
    if (hh < 0 || hh >= IMH) continue;
#pragma unroll
    for (int kw = 0; kw < 3; ++kw) {
      const int ww = w + kw - 1;
      if (ww < 0 || ww >= IMW) continue;
      acc += wv[kh * 3 + kw] * src[hh * IMW + ww];
    }
  }
  y2[(size_t)bc * HW + h * IMW + w] = acc;
}

// ---------------------------------------------------------------------------
// K3: fused conv2 (64->144) + involution. No LDS, no barriers.
// Block: 256 threads = one 16x16 pixel tile, 2 of the 16 groups.
// Grid: B * 8 * 64 = 4096 blocks (8 resident/CU -> ~100% occupancy).
// Phase 1: per-thread dynamic weights (2 groups x 9 taps), y2 coalesced
//          global reads, w2 via uniform s_load_dwordx4.
// Border: OOB taps folded into weights (weight *= 0, address clamped)
//          -> branchless phase 2, taps read x through L1 (7x in-tile reuse).
// ---------------------------------------------------------------------------
__global__ __launch_bounds__(256) void k_conv2invol(const float* __restrict__ x,
                                                    const float* __restrict__ y2,
                                                    const float* __restrict__ w2,
                                                    const float* __restrict__ b2,
                                                    float* __restrict__ out) {
  const int blk  = blockIdx.x;         // (b*8 + gp)*64 + tile
  const int tile = blk & 63;
  const int gp   = (blk >> 6) & 7;     // group pair
  const int b    = blk >> 9;
  const int g0   = gp * 2;
  const int tid  = threadIdx.x;
  const int tr   = tid >> 4;
  const int tc   = tid & 15;
  const int h    = (tile >> 3) * 16 + tr;
  const int w    = (tile & 7) * 16 + tc;
  const int p    = h * IMW + w;

  // ---- phase 1: dynamic weights for this pixel, groups g0, g0+1 ----
  float wv[2][9];
#pragma unroll
  for (int q = 0; q < 2; ++q)
#pragma unroll
    for (int j = 0; j < 9; ++j) wv[q][j] = b2[(g0 + q) * 9 + j];

  const float* y2p = y2 + (size_t)b * CR * HW + p;
#pragma unroll 1
  for (int c = 0; c < CR; c += 4) {
    const float v0 = y2p[(size_t)(c + 0) * HW];
    const float v1 = y2p[(size_t)(c + 1) * HW];
    const float v2 = y2p[(size_t)(c + 2) * HW];
    const float v3 = y2p[(size_t)(c + 3) * HW];
#pragma unroll
    for (int q = 0; q < 2; ++q)
#pragma unroll
      for (int j = 0; j < 9; ++j) {
        const float4 wq = *(const float4*)(w2 + ((g0 + q) * 9 + j) * CR + c); // uniform
        wv[q][j] += wq.x * v0 + wq.y * v1 + wq.z * v2 + wq.w * v3;
      }
  }

  // ---- fold borders into the weights; precompute clamped tap offsets ----
  const int   hcl[3] = {h > 0 ? h - 1 : 0, h, h < IMH - 1 ? h + 1 : IMH - 1};
  const int   wcl[3] = {w > 0 ? w - 1 : 0, w, w < IMW - 1 ? w + 1 : IMW - 1};
  const float mr[3]  = {h > 0 ? 1.f : 0.f, 1.f, h < IMH - 1 ? 1.f : 0.f};
  const float mc[3]  = {w > 0 ? 1.f : 0.f, 1.f, w < IMW - 1 ? 1.f : 0.f};
  int rel[9];
#pragma unroll
  for (int kh = 0; kh < 3; ++kh)
#pragma unroll
    for (int kw = 0; kw < 3; ++kw) {
      rel[kh * 3 + kw] = hcl[kh] * IMW + wcl[kw];
      const float m = mr[kh] * mc[kw];
      wv[0][kh * 3 + kw] *= m;
      wv[1][kh * 3 + kw] *= m;
    }

  // ---- phase 2: involution, branchless taps through L1 ----
  const float* xb = x + (size_t)b * CIN * HW;
  float*       ob = out + (size_t)b * CIN * HW;

#pragma unroll
  for (int q = 0; q < 2; ++q) {
#pragma unroll 2
    for (int cc = 0; cc < GC; ++cc) {
      const int ch = (g0 + q) * GC + cc;
      const float* xp = xb + (size_t)ch * HW;
      float acc = 0.f;
#pragma unroll
      for (int j = 0; j < 9; ++j) acc += wv[q][j] * xp[rel[j]];
      ob[(size_t)ch * HW + p] = acc;
    }
  }
}

extern "C" void kernel_launch(void* const* d_in, const int* in_sizes, int n_in,
                              void* d_out, int out_size, void* d_ws, size_t ws_size,
                              hipStream_t stream) {
  const float* x  = (const float*)d_in[0];
  const float* w1 = (const float*)d_in[1];
  const float* b1 = (const float*)d_in[2];
  const float* wd = (const float*)d_in[3];
  const float* bd = (const float*)d_in[4];
  const float* w2 = (const float*)d_in[5];
  const float* b2 = (const float*)d_in[6];
  float* out = (float*)d_out;

  float* y1 = (float*)d_ws;                       // 8*64*16384 f32 = 33.5 MB
  float* y2 = y1 + (size_t)8 * CR * HW;           // another 33.5 MB

  k_conv1<<<dim3(1024), dim3(256), 0, stream>>>(x, w1, b1, y1);
  k_dw<<<dim3(32768), dim3(256), 0, stream>>>(y1, wd, bd, y2);
  k_conv2invol<<<dim3(4096), dim3(256), 0, stream>>>(x, y2, w2, b2, out);
}

// Round 4
// 375.075 us; speedup vs baseline: 2.2344x; 1.3099x over previous
//
#include <hip/hip_runtime.h>
#include <hip/hip_bf16.h>

#define HW    16384   // 128*128
#define IMW   128
#define IMH   128
#define CIN   256
#define CR    64
#define G     16
#define GC    16

typedef __attribute__((ext_vector_type(8))) short short8;
typedef __attribute__((ext_vector_type(4))) float floatx4;

static __device__ __forceinline__ short f2bf(float f) {
  union { float f; unsigned u; } v; v.f = f;
  unsigned r = v.u + 0x7fffu + ((v.u >> 16) & 1u);   // RNE
  return (short)(r >> 16);
}
static __device__ __forceinline__ float bf2f(short s) {
  union { unsigned u; float f; } v; v.u = ((unsigned)(unsigned short)s) << 16;
  return v.f;
}

// ---------------------------------------------------------------------------
// K0: convert w1 (fp32 [64][256]) -> bf16, row-major. 64 blocks x 256.
// ---------------------------------------------------------------------------
__global__ __launch_bounds__(256) void k_cvt_w1(const float* __restrict__ w1,
                                                short* __restrict__ w1b) {
  const int i = blockIdx.x * 256 + threadIdx.x;      // 16384 elements
  w1b[i] = f2bf(w1[i]);
}

// ---------------------------------------------------------------------------
// K1: 1x1 conv 256->64 as bf16 MFMA GEMM: y1 = w1[64x256] * x[256xHW].
// Block 256 = 4 waves; wave handles 16 pixels x all 64 outputs (4 M-tiles,
// 16x16x32 MFMA, K-loop 8 steps). a_frag: 16B load from bf16 w1
// (A[m=lane&15][k=quad*8+j]); b_frag: 8 strided fp32 x loads, cvt in reg.
// Output stored bf16 (y1b). Grid: 8 * 256 = 2048 blocks.
// ---------------------------------------------------------------------------
__global__ __launch_bounds__(256) void k_conv1_mfma(const float* __restrict__ x,
                                                    const short* __restrict__ w1b,
                                                    const float* __restrict__ b1,
                                                    short* __restrict__ y1b) {
  const int blk  = blockIdx.x;          // b*256 + pixel-tile
  const int b    = blk >> 8;
  const int pt   = blk & 255;
  const int wave = threadIdx.x >> 6;
  const int lane = threadIdx.x & 63;
  const int quad = lane >> 4;
  const int l16  = lane & 15;
  const int p    = pt * 64 + wave * 16 + l16;

  const float* xb = x + (size_t)b * CIN * HW + p;

  floatx4 acc[4];
#pragma unroll
  for (int mt = 0; mt < 4; ++mt)
#pragma unroll
    for (int r = 0; r < 4; ++r) acc[mt][r] = b1[mt * 16 + quad * 4 + r];

#pragma unroll 1
  for (int kk = 0; kk < CIN; kk += 32) {
    short8 afrag[4];
#pragma unroll
    for (int mt = 0; mt < 4; ++mt)
      afrag[mt] = *(const short8*)(w1b + (mt * 16 + l16) * CIN + kk + quad * 8);
    float xv[8];
#pragma unroll
    for (int j = 0; j < 8; ++j)
      xv[j] = xb[(size_t)(kk + quad * 8 + j) * HW];
    short8 bfrag;
#pragma unroll
    for (int j = 0; j < 8; ++j) bfrag[j] = f2bf(xv[j]);
#pragma unroll
    for (int mt = 0; mt < 4; ++mt)
      acc[mt] = __builtin_amdgcn_mfma_f32_16x16x32_bf16(afrag[mt], bfrag, acc[mt], 0, 0, 0);
  }

  short* yb = y1b + (size_t)b * CR * HW + p;
#pragma unroll
  for (int mt = 0; mt < 4; ++mt)
#pragma unroll
    for (int r = 0; r < 4; ++r)
      yb[(size_t)(mt * 16 + quad * 4 + r) * HW] = f2bf(acc[mt][r]);
}

// ---------------------------------------------------------------------------
// K2: depthwise 3x3 over y1b (bf16 in/out), zero pad 1.
// Thread: 1 col x 4 rows (18 loads / 4 outputs). Block: 128 cols x 8 rows.
// Grid: 8 * 64 * 16 = 8192.
// ---------------------------------------------------------------------------
__global__ __launch_bounds__(256) void k_dw(const short* __restrict__ y1b,
                                            const float* __restrict__ wd,
                                            const float* __restrict__ bd,
                                            short* __restrict__ y2b) {
  const int blk   = blockIdx.x;         // b*1024 + c*16 + strip
  const int strip = blk & 15;
  const int c     = (blk >> 4) & 63;
  const int b     = blk >> 10;
  const int w     = threadIdx.x & 127;
  const int rg    = threadIdx.x >> 7;
  const int r0    = strip * 8 + rg * 4;

  const short* src = y1b + (size_t)(b * CR + c) * HW;

  const int   wm1 = w > 0 ? w - 1 : 0;
  const int   wp1 = w < IMW - 1 ? w + 1 : IMW - 1;
  const float mcl = w > 0 ? 1.f : 0.f;
  const float mcr = w < IMW - 1 ? 1.f : 0.f;

  float rowv[6][3];
#pragma unroll
  for (int i = 0; i < 6; ++i) {
    const int rr = r0 - 1 + i;
    const int rc = rr < 0 ? 0 : (rr > IMH - 1 ? IMH - 1 : rr);
    const float mr = (rr < 0 || rr > IMH - 1) ? 0.f : 1.f;
    const short* row = src + rc * IMW;
    rowv[i][0] = mr * mcl * bf2f(row[wm1]);
    rowv[i][1] = mr * bf2f(row[w]);
    rowv[i][2] = mr * mcr * bf2f(row[wp1]);
  }

  float wv[9];
#pragma unroll
  for (int j = 0; j < 9; ++j) wv[j] = wd[c * 9 + j];
  const float bias = bd[c];

  short* dst = y2b + (size_t)(b * CR + c) * HW + r0 * IMW + w;
#pragma unroll
  for (int i = 0; i < 4; ++i) {
    float acc = bias;
#pragma unroll
    for (int kh = 0; kh < 3; ++kh)
#pragma unroll
      for (int kw = 0; kw < 3; ++kw)
        acc += wv[kh * 3 + kw] * rowv[i + kh][kw];
    dst[i * IMW] = f2bf(acc);
  }
}

// ---------------------------------------------------------------------------
// K3: fused conv2 (64->144) + involution. No LDS, no barriers.
// Block: 256 threads = one 16x16 pixel tile, 2 of the 16 groups.
// Grid: B * 8 * 64 = 4096 blocks. y2 read as bf16.
// ---------------------------------------------------------------------------
__global__ __launch_bounds__(256) void k_conv2invol(const float* __restrict__ x,
                                                    const short* __restrict__ y2b,
                                                    const float* __restrict__ w2,
                                                    const float* __restrict__ b2,
                                                    float* __restrict__ out) {
  const int blk  = blockIdx.x;         // (b*8 + gp)*64 + tile
  const int tile = blk & 63;
  const int gp   = (blk >> 6) & 7;
  const int b    = blk >> 9;
  const int g0   = gp * 2;
  const int tid  = threadIdx.x;
  const int tr   = tid >> 4;
  const int tc   = tid & 15;
  const int h    = (tile >> 3) * 16 + tr;
  const int w    = (tile & 7) * 16 + tc;
  const int p    = h * IMW + w;

  // ---- phase 1: dynamic weights for this pixel, groups g0, g0+1 ----
  float wv[2][9];
#pragma unroll
  for (int q = 0; q < 2; ++q)
#pragma unroll
    for (int j = 0; j < 9; ++j) wv[q][j] = b2[(g0 + q) * 9 + j];

  const short* y2p = y2b + (size_t)b * CR * HW + p;
#pragma unroll 1
  for (int c = 0; c < CR; c += 4) {
    const float v0 = bf2f(y2p[(size_t)(c + 0) * HW]);
    const float v1 = bf2f(y2p[(size_t)(c + 1) * HW]);
    const float v2 = bf2f(y2p[(size_t)(c + 2) * HW]);
    const float v3 = bf2f(y2p[(size_t)(c + 3) * HW]);
#pragma unroll
    for (int q = 0; q < 2; ++q)
#pragma unroll
      for (int j = 0; j < 9; ++j) {
        const float4 wq = *(const float4*)(w2 + ((g0 + q) * 9 + j) * CR + c); // uniform
        wv[q][j] += wq.x * v0 + wq.y * v1 + wq.z * v2 + wq.w * v3;
      }
  }

  // ---- fold borders into weights; clamped tap offsets ----
  const int   hcl[3] = {h > 0 ? h - 1 : 0, h, h < IMH - 1 ? h + 1 : IMH - 1};
  const int   wcl[3] = {w > 0 ? w - 1 : 0, w, w < IMW - 1 ? w + 1 : IMW - 1};
  const float mr[3]  = {h > 0 ? 1.f : 0.f, 1.f, h < IMH - 1 ? 1.f : 0.f};
  const float mc[3]  = {w > 0 ? 1.f : 0.f, 1.f, w < IMW - 1 ? 1.f : 0.f};
  int rel[9];
#pragma unroll
  for (int kh = 0; kh < 3; ++kh)
#pragma unroll
    for (int kw = 0; kw < 3; ++kw) {
      rel[kh * 3 + kw] = hcl[kh] * IMW + wcl[kw];
      const float m = mr[kh] * mc[kw];
      wv[0][kh * 3 + kw] *= m;
      wv[1][kh * 3 + kw] *= m;
    }

  // ---- phase 2: involution, branchless taps through L1 ----
  const float* xb = x + (size_t)b * CIN * HW;
  float*       ob = out + (size_t)b * CIN * HW;

#pragma unroll
  for (int q = 0; q < 2; ++q) {
#pragma unroll 2
    for (int cc = 0; cc < GC; ++cc) {
      const int ch = (g0 + q) * GC + cc;
      const float* xp = xb + (size_t)ch * HW;
      float acc = 0.f;
#pragma unroll
      for (int j = 0; j < 9; ++j) acc += wv[q][j] * xp[rel[j]];
      ob[(size_t)ch * HW + p] = acc;
    }
  }
}

extern "C" void kernel_launch(void* const* d_in, const int* in_sizes, int n_in,
                              void* d_out, int out_size, void* d_ws, size_t ws_size,
                              hipStream_t stream) {
  const float* x  = (const float*)d_in[0];
  const float* w1 = (const float*)d_in[1];
  const float* b1 = (const float*)d_in[2];
  const float* wd = (const float*)d_in[3];
  const float* bd = (const float*)d_in[4];
  const float* w2 = (const float*)d_in[5];
  const float* b2 = (const float*)d_in[6];
  float* out = (float*)d_out;

  // ws layout: w1b bf16 (32 KB, padded to 64 KB) | y1b bf16 16.7 MB | y2b bf16 16.7 MB
  short* w1b = (short*)d_ws;
  short* y1b = (short*)((char*)d_ws + 65536);
  short* y2b = y1b + (size_t)8 * CR * HW;

  k_cvt_w1<<<dim3(64), dim3(256), 0, stream>>>(w1, w1b);
  k_conv1_mfma<<<dim3(2048), dim3(256), 0, stream>>>(x, w1b, b1, y1b);
  k_dw<<<dim3(8192), dim3(256), 0, stream>>>(y1b, wd, bd, y2b);
  k_conv2invol<<<dim3(4096), dim3(256), 0, stream>>>(x, y2b, w2, b2, out);
}